// Round 24
// baseline (56.071 us; speedup 1.0000x reference)
//
#include <hip/hip_runtime.h>

#define NB 16
#define NL 2048
#define NS 2048
#define NE 64
#define ND 64

typedef float floatx4 __attribute__((ext_vector_type(4)));
typedef _Float16 half8 __attribute__((ext_vector_type(8)));
typedef __fp16 half2v __attribute__((ext_vector_type(2)));  // cvt_pkrtz's return type

union H8 { half8 v; half2v h2[4]; };

__device__ __forceinline__ half8 cvt8(floatx4 a, floatx4 b) {
  H8 h;
  h.h2[0] = __builtin_amdgcn_cvt_pkrtz(a[0], a[1]);
  h.h2[1] = __builtin_amdgcn_cvt_pkrtz(a[2], a[3]);
  h.h2[2] = __builtin_amdgcn_cvt_pkrtz(b[0], b[1]);
  h.h2[3] = __builtin_amdgcn_cvt_pkrtz(b[2], b[3]);
  return h.v;
}

// async 16B/lane global->LDS. LDS dest is wave-uniform base + lane*16.
__device__ __forceinline__ void async16(void* l, const void* g) {
  __builtin_amdgcn_global_load_lds((__attribute__((address_space(1))) void*)g,
                                   (__attribute__((address_space(3))) void*)l, 16, 0, 0);
}

// kappa: contraction-slot -> key permutation making PV B-frag lane-local
// (closed within each 32-key group). kinv is its inverse.
__device__ __forceinline__ int kinv(int y) {
  return (y & 0x23) | ((y & 8) << 1) | ((y & 4) << 1) | ((y & 16) >> 2);
}

// ---------- prep: blocks [0,512) V-transpose, [512,1536) K-convert ----------
__global__ __launch_bounds__(256) void prep_k(const float* __restrict__ V,
                                              const float* __restrict__ K,
                                              _Float16* __restrict__ Vt,
                                              _Float16* __restrict__ Kh,
                                              int do_k) {
  __shared__ __align__(16) _Float16 Vl[64][72];  // [d][kappa-pos]
  const int bid = blockIdx.x;
  const int t = threadIdx.x;

  if (bid < 512) {  // ---- V -> V^T fp16 [b][d][s], kappa-permuted + swizzled
    const int b = bid >> 5;
    const int s0 = (bid & 31) * 64;
    {
      int sl = t & 63;
      int dg = t >> 6;
      const float* src = V + ((size_t)(b * NS + s0 + sl)) * ND + dg * 16;
      int x = kinv(sl);
      #pragma unroll
      for (int c = 0; c < 4; ++c) {
        floatx4 v = *(const floatx4*)(src + c * 4);
        #pragma unroll
        for (int e = 0; e < 4; ++e) Vl[dg * 16 + c * 4 + e][x] = (_Float16)v[e];
      }
    }
    __syncthreads();
    {
      int d = t & 63;
      int xg = t >> 6;
      int dk = (d & 7) << 3;
      #pragma unroll
      for (int h = 0; h < 2; ++h) {
        int x = xg * 16 + h * 8;
        half8 v = *(const half8*)&Vl[d][x];
        *(half8*)(Vt + ((size_t)(b * ND + d)) * NS + s0 + (x ^ dk)) = v;
      }
    }
  } else {  // ---- K fp32 -> fp16, swizzled columns
    if (!do_k) return;
    int c = (bid - 512) * 256 + t;
    int j = c & 7;
    int s = (c >> 3) & (NS - 1);
    int b = c >> 14;
    const float* src = K + ((size_t)(b * NS + s)) * NE + j * 8;
    half8 h = cvt8(*(const floatx4*)src, *(const floatx4*)(src + 4));
    *(half8*)(Kh + ((size_t)(b * NS + s)) * NE + (j ^ (s & 7)) * 8) = h;
  }
}

// ---------- flash attention: 128-q blocks, 128-key tiles, 8 waves -----------
// triple-buffered LDS, ONE barrier/tile; row-sum via MFMA(ones)
// split epilogue: g=0 reduces sub0, g=1 reduces sub1 (both halves store)
// XCD-aware remap: each XCD owns 2 batches -> K/V L2-resident
template<bool KH16>
__global__ __launch_bounds__(512) void attn_k(const float* __restrict__ Q,
                                              const void* __restrict__ Ksrc,
                                              const _Float16* __restrict__ Vtp,
                                              _Float16* __restrict__ Vatt,
                                              const float* __restrict__ Mf,
                                              _Float16* __restrict__ Mh) {
  __shared__ __align__(16) char smem[98304];  // K 3x16K @0, V 3x16K @49152
  const int tid = threadIdx.x;
  const int wid = tid >> 6, lane = tid & 63;
  const int lr = lane & 15, lg = lane >> 4;
  const int g = wid & 1;        // key-half of the 128-key tile (64 keys)
  const int qh = wid >> 1;      // q-quarter (32 q each, 0..3)
  // XCD-aware bijective remap: XCD L%8 hosts batches {2*xcd, 2*xcd+1}
  const int L = blockIdx.y * 16 + blockIdx.x;   // 0..255
  const int b = (L & 7) * 2 + ((L >> 3) & 1);
  const int qx = L >> 4;                        // 0..15
  const int qbase = qx * 128 + qh * 32;
  const _Float16* Kh = (const _Float16*)Ksrc;
  const float* Kf = (const float*)Ksrc;

  // Q B-frags with scale*log2(e) pre-folded. [col=q=lr][k = kk*32+lg*8+j]
  constexpr float SC = 0.18033688f;  // (1/8) * log2(e)
  half8 qf[2][2];
  #pragma unroll
  for (int sub = 0; sub < 2; ++sub)
    #pragma unroll
    for (int kk = 0; kk < 2; ++kk) {
      const float* qp = Q + ((size_t)(b * NL + qbase + sub * 16 + lr)) * NE + kk * 32 + lg * 8;
      floatx4 a = *(const floatx4*)qp, c = *(const floatx4*)(qp + 4);
      qf[sub][kk] = cvt8(a * SC, c * SC);
    }

  half8 ones;
  #pragma unroll
  for (int i = 0; i < 8; ++i) ones[i] = (_Float16)1.0f;

  floatx4 oacc[2][4], lacc[2];
  #pragma unroll
  for (int s = 0; s < 2; ++s) {
    lacc[s] = (floatx4){0.f, 0.f, 0.f, 0.f};
    #pragma unroll
    for (int m = 0; m < 4; ++m) oacc[s][m] = (floatx4){0.f, 0.f, 0.f, 0.f};
  }

  // hoisted swizzled LDS read offsets (invariant across tiles)
  int kOff[4][2], vOff[2][4];
  #pragma unroll
  for (int mt = 0; mt < 4; ++mt)
    #pragma unroll
    for (int kk = 0; kk < 2; ++kk) {
      int row = g * 64 + mt * 16 + lr, col = kk * 32 + lg * 8;
      kOff[mt][kk] = (row * 128 + col * 2) ^ ((row & 7) << 4);
    }
  #pragma unroll
  for (int kk = 0; kk < 2; ++kk)
    #pragma unroll
    for (int mt = 0; mt < 4; ++mt) {
      int row = mt * 16 + lr;
      vOff[kk][mt] = row * 256 + g * 128 + (((kk * 32 + lg * 8) * 2) ^ ((row & 7) << 4));
    }

  // 8 waves stage 32KB per 128-key tile: 2 async16 per wave K, 2 V
  auto stageV = [&](int buf, int s0) {
    #pragma unroll
    for (int i = 0; i < 2; ++i) {
      int co = (wid * 2 + i) * 1024;
      int o = co + lane * 16;
      int row = o >> 8, c16 = (o >> 4) & 15;
      async16(smem + 49152 + buf * 16384 + co,
              Vtp + ((size_t)(b * ND + row)) * NS + s0 + c16 * 8);
    }
  };
  auto stageK = [&](int buf, int s0) {
    if constexpr (KH16) {
      #pragma unroll
      for (int i = 0; i < 2; ++i) {
        int co = (wid * 2 + i) * 1024;
        int o = co + lane * 16;
        int row = o >> 7, c8 = (o >> 4) & 7;
        async16(smem + buf * 16384 + co,
                Kh + ((size_t)(b * NS + s0 + row)) * NE + c8 * 8);
      }
    } else {
      int row = tid >> 2, cg = (tid & 3) * 16;
      const float* kp = Kf + ((size_t)(b * NS + s0 + row)) * NE + cg;
      #pragma unroll
      for (int c = 0; c < 2; ++c) {
        half8 h = cvt8(*(const floatx4*)(kp + c * 8), *(const floatx4*)(kp + c * 8 + 4));
        int col = cg + c * 8;
        *(half8*)(smem + buf * 16384 + ((row * 128 + col * 2) ^ ((row & 7) << 4))) = h;
      }
    }
  };

  stageK(0, 0); stageV(0, 0);

  int br = 0;
  for (int t = 0; t < NS / 128; ++t) {
    int bn = (br == 2) ? 0 : br + 1;
    if (t + 1 < NS / 128) {
      stageK(bn, (t + 1) * 128); stageV(bn, (t + 1) * 128);
      if constexpr (KH16) {
        asm volatile("s_waitcnt vmcnt(4)" ::: "memory");
        __builtin_amdgcn_s_barrier();
      } else __syncthreads();
    } else {
      if constexpr (KH16) {
        asm volatile("s_waitcnt vmcnt(0)" ::: "memory");
        __builtin_amdgcn_s_barrier();
      } else __syncthreads();
    }

    const char* kb = smem + br * 16384;
    const char* vb = smem + 49152 + br * 16384;

    // K A-frags: this wave's 64 keys
    half8 kf[4][2];
    #pragma unroll
    for (int mt = 0; mt < 4; ++mt)
      #pragma unroll
      for (int kk = 0; kk < 2; ++kk)
        kf[mt][kk] = *(const half8*)(kb + kOff[mt][kk]);

    H8 bf[2][2];
    #pragma unroll
    for (int sub = 0; sub < 2; ++sub) {
      floatx4 sacc[4];
      #pragma unroll
      for (int mt = 0; mt < 4; ++mt) sacc[mt] = (floatx4){0.f, 0.f, 0.f, 0.f};
      __builtin_amdgcn_s_setprio(1);
      #pragma unroll
      for (int kk = 0; kk < 2; ++kk)
        #pragma unroll
        for (int mt = 0; mt < 4; ++mt)
          sacc[mt] = __builtin_amdgcn_mfma_f32_16x16x32_f16(kf[mt][kk], qf[sub][kk], sacc[mt], 0, 0, 0);
      __builtin_amdgcn_s_setprio(0);

      // p = exp2(s); pack straight into kappa-local B-frags
      #pragma unroll
      for (int mt = 0; mt < 4; ++mt) {
        float p0 = __builtin_amdgcn_exp2f(sacc[mt][0]);
        float p1 = __builtin_amdgcn_exp2f(sacc[mt][1]);
        float p2 = __builtin_amdgcn_exp2f(sacc[mt][2]);
        float p3 = __builtin_amdgcn_exp2f(sacc[mt][3]);
        bf[sub][mt >> 1].h2[(mt & 1) * 2]     = __builtin_amdgcn_cvt_pkrtz(p0, p1);
        bf[sub][mt >> 1].h2[(mt & 1) * 2 + 1] = __builtin_amdgcn_cvt_pkrtz(p2, p3);
      }
    }

    // PV^T + row-sum via MFMA(ones): lacc[sub] accumulates sum_k P[q,k]
    __builtin_amdgcn_s_setprio(1);
    #pragma unroll
    for (int kk = 0; kk < 2; ++kk) {
      #pragma unroll
      for (int mt = 0; mt < 4; ++mt) {
        half8 vt = *(const half8*)(vb + vOff[kk][mt]);
        oacc[0][mt] = __builtin_amdgcn_mfma_f32_16x16x32_f16(vt, bf[0][kk].v, oacc[0][mt], 0, 0, 0);
        oacc[1][mt] = __builtin_amdgcn_mfma_f32_16x16x32_f16(vt, bf[1][kk].v, oacc[1][mt], 0, 0, 0);
      }
      lacc[0] = __builtin_amdgcn_mfma_f32_16x16x32_f16(ones, bf[0][kk].v, lacc[0], 0, 0, 0);
      lacc[1] = __builtin_amdgcn_mfma_f32_16x16x32_f16(ones, bf[1][kk].v, lacc[1], 0, 0, 0);
    }
    __builtin_amdgcn_s_setprio(0);
    br = bn;
  }

  __syncthreads();  // last tile's reads complete everywhere before smem reuse

  // split epilogue per q-quarter: full result for sub s = g0.partial + g1.partial.
  // g=1 publishes its sub0 partial (region A); g=0 publishes its sub1 (region B);
  // then g=0 reduces+stores sub0, g=1 reduces+stores sub1.
  {
    char* base = smem + qh * 16384;
    char* wr = base + (g ? 0 : 8192);   // g1 -> A, g0 -> B
    char* rd = base + (g ? 8192 : 0);   // g1 reads B, g0 reads A
    const int ps = g ? 0 : 1;           // sub published
    const int rs = g;                   // sub reduced by this wave
    #pragma unroll
    for (int mt = 0; mt < 4; ++mt)
      *(floatx4*)(wr + lane * 64 + mt * 16) = oacc[ps][mt];
    if (lg == 0) *(float*)(wr + 4096 + lr * 4) = lacc[ps][0];
    __syncthreads();
    {
      float lt = lacc[rs][0] + *(const float*)(rd + 4096 + lr * 4);
      float inv = __builtin_amdgcn_rcpf(lt);
      int l = qbase + rs * 16 + lr;
      #pragma unroll
      for (int mt = 0; mt < 4; ++mt) {
        floatx4 o = oacc[rs][mt] + *(const floatx4*)(rd + lane * 64 + mt * 16);
        #pragma unroll
        for (int r = 0; r < 4; ++r) {
          int d = mt * 16 + lg * 4 + r;
          int lsw = (l & ~63) | ((l & 63) ^ ((d & 7) << 3));
          Vatt[((size_t)(b * ND + d)) * NL + lsw] = (_Float16)(o[r] * inv);
        }
      }
    }
  }

  // ---- tail: this block converts 1/256 of mlp fp32 -> fp16 (swizzled) ----
  if constexpr (KH16) {
    int mb = blockIdx.y * 16 + blockIdx.x;  // 0..255
    #pragma unroll
    for (int q = 0; q < 4; ++q) {
      int c = mb * 2048 + q * 512 + tid;
      int j = c & 255, p = c >> 8;
      const float* src = Mf + (size_t)p * NL + j * 8;
      half8 h = cvt8(*(const floatx4*)src, *(const floatx4*)(src + 4));
      int jo = (j & ~7) | ((j & 7) ^ (p & 7));
      *(half8*)(Mh + (size_t)p * NL + jo * 8) = h;
    }
  }
}

// ---------- mix: out[b,p,d] = sum_l mlp[p,l] * Vatt^T[(b,d)][l] -------------
// 4 waves (mw M-half, kh K-half); double-buffered 64KB -> 2 blocks/CU;
// single barrier/tile (stage AFTER barrier; reads register-consumed pre-barrier)
// XCD-aware remap: each XCD owns 4 p-tiles -> A-panel L2-resident
template<bool A16>
__global__ __launch_bounds__(256) void mix_k(const void* __restrict__ Asrc,
                                             const _Float16* __restrict__ Bsrc,
                                             float* __restrict__ out) {
  // A0 @0, A1 @16384, B0 @32768, B1 @49152 (each: dbuf 2 x 8KB)
  __shared__ __align__(16) char smem[65536];
  const int tid = threadIdx.x;
  const int wid = tid >> 6, lane = tid & 63;
  const int lr = lane & 15, lg = lane >> 4;
  const int kh = wid & 1;       // K-half
  const int mw = wid >> 1;      // M-half (32 rows)
  // XCD-aware bijective remap of (p-tile, batch): XCD L%8 owns p-tiles {4x..4x+3}
  const int L = blockIdx.y * 32 + blockIdx.x;   // 0..511
  const int i = L >> 3;                          // 0..63
  const int p0 = ((L & 7) * 4 + (i & 3)) * 64;
  const int b = i >> 2;
  const _Float16* Ah = (const _Float16*)Asrc;
  const float* Af = (const float*)Asrc;

  floatx4 acc[2][4];
  #pragma unroll
  for (int mt = 0; mt < 2; ++mt)
    #pragma unroll
    for (int nt = 0; nt < 4; ++nt) acc[mt][nt] = (floatx4){0.f, 0.f, 0.f, 0.f};

  // per tile: wave (kh,mw) stages quarter of A[kh] and B[kh] (8 async16)
  auto stage = [&](int buf, int t) {
    int k0 = kh * (NL / 2) + t * 64;
    if constexpr (A16) {
      #pragma unroll
      for (int i2 = 0; i2 < 4; ++i2) {
        int co = (mw * 4 + i2) * 1024;
        int o = co + lane * 16;
        int row = o >> 7, c8 = (o >> 4) & 7;
        async16(smem + kh * 16384 + buf * 8192 + co,
                Ah + ((size_t)(p0 + row)) * NL + k0 + c8 * 8);
      }
    } else {
      int row = (lane & 31) + mw * 32, cg = (lane >> 5) * 32;
      const float* ap = Af + ((size_t)(p0 + row)) * NL + k0 + cg;
      #pragma unroll
      for (int c = 0; c < 4; ++c) {
        half8 h = cvt8(*(const floatx4*)(ap + c * 8), *(const floatx4*)(ap + c * 8 + 4));
        int col = cg + c * 8;
        *(half8*)(smem + kh * 16384 + buf * 8192 +
                  ((row * 128 + col * 2) ^ ((row & 7) << 4))) = h;
      }
    }
    #pragma unroll
    for (int i2 = 0; i2 < 4; ++i2) {
      int co = (mw * 4 + i2) * 1024;
      int o = co + lane * 16;
      int row = o >> 7, c8 = (o >> 4) & 7;
      async16(smem + 32768 + kh * 16384 + buf * 8192 + co,
              Bsrc + ((size_t)(b * ND + row)) * NL + k0 + c8 * 8);
    }
  };

  stage(0, 0);
  if constexpr (!A16) __syncthreads();

  for (int t = 0; t < 16; ++t) {
    int buf = t & 1;
    if constexpr (A16) {
      // single barrier: drain stage(t), then prefetch t+1 into buf^1 (= buf(t-1),
      // whose reads were register-consumed by every wave before it got here)
      asm volatile("s_waitcnt vmcnt(0)" ::: "memory");
      __builtin_amdgcn_s_barrier();
      if (t + 1 < 16) stage(buf ^ 1, t + 1);
    } else {
      if (t + 1 < 16) { stage(buf ^ 1, t + 1); __syncthreads(); }
    }
    const char* ab = smem + kh * 16384 + buf * 8192;
    const char* bb = smem + 32768 + kh * 16384 + buf * 8192;
    #pragma unroll
    for (int kk = 0; kk < 2; ++kk) {
      int col = kk * 32 + lg * 8;
      half8 af[2];
      #pragma unroll
      for (int mt = 0; mt < 2; ++mt) {
        int row = mw * 32 + mt * 16 + lr;
        af[mt] = *(const half8*)(ab + ((row * 128 + col * 2) ^ ((row & 7) << 4)));
      }
      __builtin_amdgcn_s_setprio(1);
      #pragma unroll
      for (int nt = 0; nt < 4; ++nt) {
        int row = nt * 16 + lr;
        half8 bfr = *(const half8*)(bb + ((row * 128 + col * 2) ^ ((row & 7) << 4)));
        #pragma unroll
        for (int mt = 0; mt < 2; ++mt)
          acc[mt][nt] = __builtin_amdgcn_mfma_f32_16x16x32_f16(af[mt], bfr, acc[mt][nt], 0, 0, 0);
      }
      __builtin_amdgcn_s_setprio(0);
    }
    if constexpr (!A16) __syncthreads();
  }

  __syncthreads();  // all compute done before smem reuse

  // reduce K-halves: kh=1 publishes (XOR-swizzled vs 128B-stride conflicts)
  if (kh == 1) {
    #pragma unroll
    for (int mt = 0; mt < 2; ++mt)
      #pragma unroll
      for (int nt = 0; nt < 4; ++nt) {
        int idx = mt * 4 + nt;
        *(floatx4*)(smem + mw * 8192 + lane * 128 + ((idx ^ (lane & 7)) * 16)) = acc[mt][nt];
      }
  }
  __syncthreads();
  if (kh == 0) {
    #pragma unroll
    for (int mt = 0; mt < 2; ++mt)
      #pragma unroll
      for (int nt = 0; nt < 4; ++nt) {
        int idx = mt * 4 + nt;
        acc[mt][nt] += *(const floatx4*)(smem + mw * 8192 + lane * 128 + ((idx ^ (lane & 7)) * 16));
        #pragma unroll
        for (int r = 0; r < 4; ++r) {
          int p = p0 + mw * 32 + mt * 16 + lg * 4 + r;
          int d = nt * 16 + lr;
          out[((size_t)(b * NL + p)) * ND + d] = acc[mt][nt][r];
        }
      }
  }
}

extern "C" void kernel_launch(void* const* d_in, const int* in_sizes, int n_in,
                              void* d_out, int out_size, void* d_ws, size_t ws_size,
                              hipStream_t stream) {
  (void)in_sizes; (void)n_in; (void)out_size;
  const float* Q = (const float*)d_in[0];
  const float* K = (const float*)d_in[1];
  const float* V = (const float*)d_in[2];
  const float* M = (const float*)d_in[3];
  float* out = (float*)d_out;

  char* ws = (char*)d_ws;
  _Float16* Vtp  = (_Float16*)ws;                      // 4 MB  [b][d][s] kappa+swz
  _Float16* Vatt = (_Float16*)(ws + (4u << 20));       // 4 MB  [b][d][l] swz
  _Float16* Kh   = (_Float16*)(ws + (8u << 20));       // 4 MB  [b][s][e] swz
  _Float16* Mh   = (_Float16*)(ws + (12u << 20));      // 8 MB  [p][l]    swz
  bool big = ws_size >= (size_t)(20u << 20);

  if (big) {
    prep_k<<<1536, 256, 0, stream>>>(V, K, Vtp, Kh, 1);
    attn_k<true><<<dim3(16, 16), 512, 0, stream>>>(Q, Kh, Vtp, Vatt, M, Mh);
    mix_k<true><<<dim3(32, 16), 256, 0, stream>>>(Mh, Vatt, out);
  } else {
    prep_k<<<512, 256, 0, stream>>>(V, K, Vtp, Kh, 0);
    attn_k<false><<<dim3(16, 16), 512, 0, stream>>>(Q, K, Vtp, Vatt, nullptr, nullptr);
    mix_k<false><<<dim3(32, 16), 256, 0, stream>>>(M, Vatt, out);
  }
}

// Round 25
// 51.721 us; speedup vs baseline: 1.0841x; 1.0841x over previous
//
#include <hip/hip_runtime.h>

#define NB 16
#define NL 2048
#define NS 2048
#define NE 64
#define ND 64

typedef float floatx4 __attribute__((ext_vector_type(4)));
typedef _Float16 half8 __attribute__((ext_vector_type(8)));
typedef __fp16 half2v __attribute__((ext_vector_type(2)));  // cvt_pkrtz's return type

union H8 { half8 v; half2v h2[4]; };

__device__ __forceinline__ half8 cvt8(floatx4 a, floatx4 b) {
  H8 h;
  h.h2[0] = __builtin_amdgcn_cvt_pkrtz(a[0], a[1]);
  h.h2[1] = __builtin_amdgcn_cvt_pkrtz(a[2], a[3]);
  h.h2[2] = __builtin_amdgcn_cvt_pkrtz(b[0], b[1]);
  h.h2[3] = __builtin_amdgcn_cvt_pkrtz(b[2], b[3]);
  return h.v;
}

// async 16B/lane global->LDS. LDS dest is wave-uniform base + lane*16.
__device__ __forceinline__ void async16(void* l, const void* g) {
  __builtin_amdgcn_global_load_lds((__attribute__((address_space(1))) void*)g,
                                   (__attribute__((address_space(3))) void*)l, 16, 0, 0);
}

// kappa: contraction-slot -> key permutation making PV B-frag lane-local
// (closed within each 32-key group). kinv is its inverse.
__device__ __forceinline__ int kinv(int y) {
  return (y & 0x23) | ((y & 8) << 1) | ((y & 4) << 1) | ((y & 16) >> 2);
}

// ---------- prep: blocks [0,512) V-transpose, [512,1536) K-convert ----------
__global__ __launch_bounds__(256) void prep_k(const float* __restrict__ V,
                                              const float* __restrict__ K,
                                              _Float16* __restrict__ Vt,
                                              _Float16* __restrict__ Kh,
                                              int do_k) {
  __shared__ __align__(16) _Float16 Vl[64][72];  // [d][kappa-pos]
  const int bid = blockIdx.x;
  const int t = threadIdx.x;

  if (bid < 512) {  // ---- V -> V^T fp16 [b][d][s], kappa-permuted + swizzled
    const int b = bid >> 5;
    const int s0 = (bid & 31) * 64;
    {
      int sl = t & 63;
      int dg = t >> 6;
      const float* src = V + ((size_t)(b * NS + s0 + sl)) * ND + dg * 16;
      int x = kinv(sl);
      #pragma unroll
      for (int c = 0; c < 4; ++c) {
        floatx4 v = *(const floatx4*)(src + c * 4);
        #pragma unroll
        for (int e = 0; e < 4; ++e) Vl[dg * 16 + c * 4 + e][x] = (_Float16)v[e];
      }
    }
    __syncthreads();
    {
      int d = t & 63;
      int xg = t >> 6;
      int dk = (d & 7) << 3;
      #pragma unroll
      for (int h = 0; h < 2; ++h) {
        int x = xg * 16 + h * 8;
        half8 v = *(const half8*)&Vl[d][x];
        *(half8*)(Vt + ((size_t)(b * ND + d)) * NS + s0 + (x ^ dk)) = v;
      }
    }
  } else {  // ---- K fp32 -> fp16, swizzled columns
    if (!do_k) return;
    int c = (bid - 512) * 256 + t;
    int j = c & 7;
    int s = (c >> 3) & (NS - 1);
    int b = c >> 14;
    const float* src = K + ((size_t)(b * NS + s)) * NE + j * 8;
    half8 h = cvt8(*(const floatx4*)src, *(const floatx4*)(src + 4));
    *(half8*)(Kh + ((size_t)(b * NS + s)) * NE + (j ^ (s & 7)) * 8) = h;
  }
}

// ---------- flash attention: 128-q blocks, 128-key tiles, 8 waves -----------
// triple-buffered LDS, ONE barrier/tile; row-sum via MFMA(ones)
// XCD-aware remap: each XCD owns 2 batches -> K/V L2-resident
template<bool KH16>
__global__ __launch_bounds__(512) void attn_k(const float* __restrict__ Q,
                                              const void* __restrict__ Ksrc,
                                              const _Float16* __restrict__ Vtp,
                                              _Float16* __restrict__ Vatt,
                                              const float* __restrict__ Mf,
                                              _Float16* __restrict__ Mh) {
  __shared__ __align__(16) char smem[98304];  // K 3x16K @0, V 3x16K @49152
  const int tid = threadIdx.x;
  const int wid = tid >> 6, lane = tid & 63;
  const int lr = lane & 15, lg = lane >> 4;
  const int g = wid & 1;        // key-half of the 128-key tile (64 keys)
  const int qh = wid >> 1;      // q-quarter (32 q each, 0..3)
  // XCD-aware bijective remap: XCD L%8 hosts batches {2*xcd, 2*xcd+1}
  const int L = blockIdx.y * 16 + blockIdx.x;   // 0..255
  const int b = (L & 7) * 2 + ((L >> 3) & 1);
  const int qx = L >> 4;                        // 0..15
  const int qbase = qx * 128 + qh * 32;
  const _Float16* Kh = (const _Float16*)Ksrc;
  const float* Kf = (const float*)Ksrc;

  // Q B-frags with scale*log2(e) pre-folded. [col=q=lr][k = kk*32+lg*8+j]
  constexpr float SC = 0.18033688f;  // (1/8) * log2(e)
  half8 qf[2][2];
  #pragma unroll
  for (int sub = 0; sub < 2; ++sub)
    #pragma unroll
    for (int kk = 0; kk < 2; ++kk) {
      const float* qp = Q + ((size_t)(b * NL + qbase + sub * 16 + lr)) * NE + kk * 32 + lg * 8;
      floatx4 a = *(const floatx4*)qp, c = *(const floatx4*)(qp + 4);
      qf[sub][kk] = cvt8(a * SC, c * SC);
    }

  half8 ones;
  #pragma unroll
  for (int i = 0; i < 8; ++i) ones[i] = (_Float16)1.0f;

  floatx4 oacc[2][4], lacc[2];
  #pragma unroll
  for (int s = 0; s < 2; ++s) {
    lacc[s] = (floatx4){0.f, 0.f, 0.f, 0.f};
    #pragma unroll
    for (int m = 0; m < 4; ++m) oacc[s][m] = (floatx4){0.f, 0.f, 0.f, 0.f};
  }

  // hoisted swizzled LDS read offsets (invariant across tiles)
  int kOff[4][2], vOff[2][4];
  #pragma unroll
  for (int mt = 0; mt < 4; ++mt)
    #pragma unroll
    for (int kk = 0; kk < 2; ++kk) {
      int row = g * 64 + mt * 16 + lr, col = kk * 32 + lg * 8;
      kOff[mt][kk] = (row * 128 + col * 2) ^ ((row & 7) << 4);
    }
  #pragma unroll
  for (int kk = 0; kk < 2; ++kk)
    #pragma unroll
    for (int mt = 0; mt < 4; ++mt) {
      int row = mt * 16 + lr;
      vOff[kk][mt] = row * 256 + g * 128 + (((kk * 32 + lg * 8) * 2) ^ ((row & 7) << 4));
    }

  // 8 waves stage 32KB per 128-key tile: 2 async16 per wave K, 2 V
  auto stageV = [&](int buf, int s0) {
    #pragma unroll
    for (int i = 0; i < 2; ++i) {
      int co = (wid * 2 + i) * 1024;
      int o = co + lane * 16;
      int row = o >> 8, c16 = (o >> 4) & 15;
      async16(smem + 49152 + buf * 16384 + co,
              Vtp + ((size_t)(b * ND + row)) * NS + s0 + c16 * 8);
    }
  };
  auto stageK = [&](int buf, int s0) {
    if constexpr (KH16) {
      #pragma unroll
      for (int i = 0; i < 2; ++i) {
        int co = (wid * 2 + i) * 1024;
        int o = co + lane * 16;
        int row = o >> 7, c8 = (o >> 4) & 7;
        async16(smem + buf * 16384 + co,
                Kh + ((size_t)(b * NS + s0 + row)) * NE + c8 * 8);
      }
    } else {
      int row = tid >> 2, cg = (tid & 3) * 16;
      const float* kp = Kf + ((size_t)(b * NS + s0 + row)) * NE + cg;
      #pragma unroll
      for (int c = 0; c < 2; ++c) {
        half8 h = cvt8(*(const floatx4*)(kp + c * 8), *(const floatx4*)(kp + c * 8 + 4));
        int col = cg + c * 8;
        *(half8*)(smem + buf * 16384 + ((row * 128 + col * 2) ^ ((row & 7) << 4))) = h;
      }
    }
  };

  stageK(0, 0); stageV(0, 0);

  int br = 0;
  for (int t = 0; t < NS / 128; ++t) {
    int bn = (br == 2) ? 0 : br + 1;
    if (t + 1 < NS / 128) {
      stageK(bn, (t + 1) * 128); stageV(bn, (t + 1) * 128);
      if constexpr (KH16) {
        asm volatile("s_waitcnt vmcnt(4)" ::: "memory");
        __builtin_amdgcn_s_barrier();
      } else __syncthreads();
    } else {
      if constexpr (KH16) {
        asm volatile("s_waitcnt vmcnt(0)" ::: "memory");
        __builtin_amdgcn_s_barrier();
      } else __syncthreads();
    }

    const char* kb = smem + br * 16384;
    const char* vb = smem + 49152 + br * 16384;

    // K A-frags: this wave's 64 keys
    half8 kf[4][2];
    #pragma unroll
    for (int mt = 0; mt < 4; ++mt)
      #pragma unroll
      for (int kk = 0; kk < 2; ++kk)
        kf[mt][kk] = *(const half8*)(kb + kOff[mt][kk]);

    H8 bf[2][2];
    #pragma unroll
    for (int sub = 0; sub < 2; ++sub) {
      floatx4 sacc[4];
      #pragma unroll
      for (int mt = 0; mt < 4; ++mt) sacc[mt] = (floatx4){0.f, 0.f, 0.f, 0.f};
      __builtin_amdgcn_s_setprio(1);
      #pragma unroll
      for (int kk = 0; kk < 2; ++kk)
        #pragma unroll
        for (int mt = 0; mt < 4; ++mt)
          sacc[mt] = __builtin_amdgcn_mfma_f32_16x16x32_f16(kf[mt][kk], qf[sub][kk], sacc[mt], 0, 0, 0);
      __builtin_amdgcn_s_setprio(0);

      // p = exp2(s); pack straight into kappa-local B-frags
      #pragma unroll
      for (int mt = 0; mt < 4; ++mt) {
        float p0 = __builtin_amdgcn_exp2f(sacc[mt][0]);
        float p1 = __builtin_amdgcn_exp2f(sacc[mt][1]);
        float p2 = __builtin_amdgcn_exp2f(sacc[mt][2]);
        float p3 = __builtin_amdgcn_exp2f(sacc[mt][3]);
        bf[sub][mt >> 1].h2[(mt & 1) * 2]     = __builtin_amdgcn_cvt_pkrtz(p0, p1);
        bf[sub][mt >> 1].h2[(mt & 1) * 2 + 1] = __builtin_amdgcn_cvt_pkrtz(p2, p3);
      }
    }

    // PV^T + row-sum via MFMA(ones): lacc[sub] accumulates sum_k P[q,k]
    __builtin_amdgcn_s_setprio(1);
    #pragma unroll
    for (int kk = 0; kk < 2; ++kk) {
      #pragma unroll
      for (int mt = 0; mt < 4; ++mt) {
        half8 vt = *(const half8*)(vb + vOff[kk][mt]);
        oacc[0][mt] = __builtin_amdgcn_mfma_f32_16x16x32_f16(vt, bf[0][kk].v, oacc[0][mt], 0, 0, 0);
        oacc[1][mt] = __builtin_amdgcn_mfma_f32_16x16x32_f16(vt, bf[1][kk].v, oacc[1][mt], 0, 0, 0);
      }
      lacc[0] = __builtin_amdgcn_mfma_f32_16x16x32_f16(ones, bf[0][kk].v, lacc[0], 0, 0, 0);
      lacc[1] = __builtin_amdgcn_mfma_f32_16x16x32_f16(ones, bf[1][kk].v, lacc[1], 0, 0, 0);
    }
    __builtin_amdgcn_s_setprio(0);
    br = bn;
  }

  __syncthreads();  // last tile's reads complete everywhere before smem reuse

  // combine key-halves per q-quarter: g=1 publishes partials; g=0 reduce+store
  {
    char* red = smem + qh * 12288;
    if (g == 1) {
      #pragma unroll
      for (int sub = 0; sub < 2; ++sub)
        #pragma unroll
        for (int mt = 0; mt < 4; ++mt)
          *(floatx4*)(red + lane * 144 + (sub * 4 + mt) * 16) = oacc[sub][mt];
      if (lg == 0) {
        *(float*)(red + 9216 + lr * 8) = lacc[0][0];
        *(float*)(red + 9216 + lr * 8 + 4) = lacc[1][0];
      }
    }
    __syncthreads();
    if (g == 0) {
      #pragma unroll
      for (int sub = 0; sub < 2; ++sub) {
        float lt = lacc[sub][0] + *(const float*)(red + 9216 + lr * 8 + sub * 4);
        float inv = __builtin_amdgcn_rcpf(lt);
        int l = qbase + sub * 16 + lr;
        #pragma unroll
        for (int mt = 0; mt < 4; ++mt) {
          floatx4 o = oacc[sub][mt] + *(const floatx4*)(red + lane * 144 + (sub * 4 + mt) * 16);
          #pragma unroll
          for (int r = 0; r < 4; ++r) {
            int d = mt * 16 + lg * 4 + r;
            int lsw = (l & ~63) | ((l & 63) ^ ((d & 7) << 3));
            Vatt[((size_t)(b * ND + d)) * NL + lsw] = (_Float16)(o[r] * inv);
          }
        }
      }
    }
  }

  // ---- tail: this block converts 1/256 of mlp fp32 -> fp16 (swizzled) ----
  if constexpr (KH16) {
    int mb = blockIdx.y * 16 + blockIdx.x;  // 0..255
    #pragma unroll
    for (int q = 0; q < 4; ++q) {
      int c = mb * 2048 + q * 512 + tid;
      int j = c & 255, p = c >> 8;
      const float* src = Mf + (size_t)p * NL + j * 8;
      half8 h = cvt8(*(const floatx4*)src, *(const floatx4*)(src + 4));
      int jo = (j & ~7) | ((j & 7) ^ (p & 7));
      *(half8*)(Mh + (size_t)p * NL + jo * 8) = h;
    }
  }
}

// ---------- mix: out[b,p,d] = sum_l mlp[p,l] * Vatt^T[(b,d)][l] -------------
// 4 waves (mw M-half, kh K-half); double-buffered 64KB -> 2 blocks/CU;
// single barrier/tile (stage AFTER barrier; reads register-consumed pre-barrier)
// XCD-aware remap: each XCD owns 4 p-tiles -> A-panel L2-resident
template<bool A16>
__global__ __launch_bounds__(256) void mix_k(const void* __restrict__ Asrc,
                                             const _Float16* __restrict__ Bsrc,
                                             float* __restrict__ out) {
  // A0 @0, A1 @16384, B0 @32768, B1 @49152 (each: dbuf 2 x 8KB)
  __shared__ __align__(16) char smem[65536];
  const int tid = threadIdx.x;
  const int wid = tid >> 6, lane = tid & 63;
  const int lr = lane & 15, lg = lane >> 4;
  const int kh = wid & 1;       // K-half
  const int mw = wid >> 1;      // M-half (32 rows)
  // XCD-aware bijective remap of (p-tile, batch): XCD L%8 owns p-tiles {4x..4x+3}
  const int L = blockIdx.y * 32 + blockIdx.x;   // 0..511
  const int i = L >> 3;                          // 0..63
  const int p0 = ((L & 7) * 4 + (i & 3)) * 64;
  const int b = i >> 2;
  const _Float16* Ah = (const _Float16*)Asrc;
  const float* Af = (const float*)Asrc;

  floatx4 acc[2][4];
  #pragma unroll
  for (int mt = 0; mt < 2; ++mt)
    #pragma unroll
    for (int nt = 0; nt < 4; ++nt) acc[mt][nt] = (floatx4){0.f, 0.f, 0.f, 0.f};

  // per tile: wave (kh,mw) stages quarter of A[kh] and B[kh] (8 async16)
  auto stage = [&](int buf, int t) {
    int k0 = kh * (NL / 2) + t * 64;
    if constexpr (A16) {
      #pragma unroll
      for (int i2 = 0; i2 < 4; ++i2) {
        int co = (mw * 4 + i2) * 1024;
        int o = co + lane * 16;
        int row = o >> 7, c8 = (o >> 4) & 7;
        async16(smem + kh * 16384 + buf * 8192 + co,
                Ah + ((size_t)(p0 + row)) * NL + k0 + c8 * 8);
      }
    } else {
      int row = (lane & 31) + mw * 32, cg = (lane >> 5) * 32;
      const float* ap = Af + ((size_t)(p0 + row)) * NL + k0 + cg;
      #pragma unroll
      for (int c = 0; c < 4; ++c) {
        half8 h = cvt8(*(const floatx4*)(ap + c * 8), *(const floatx4*)(ap + c * 8 + 4));
        int col = cg + c * 8;
        *(half8*)(smem + kh * 16384 + buf * 8192 +
                  ((row * 128 + col * 2) ^ ((row & 7) << 4))) = h;
      }
    }
    #pragma unroll
    for (int i2 = 0; i2 < 4; ++i2) {
      int co = (mw * 4 + i2) * 1024;
      int o = co + lane * 16;
      int row = o >> 7, c8 = (o >> 4) & 7;
      async16(smem + 32768 + kh * 16384 + buf * 8192 + co,
              Bsrc + ((size_t)(b * ND + row)) * NL + k0 + c8 * 8);
    }
  };

  stage(0, 0);
  if constexpr (!A16) __syncthreads();

  for (int t = 0; t < 16; ++t) {
    int buf = t & 1;
    if constexpr (A16) {
      // single barrier: drain stage(t), then prefetch t+1 into buf^1 (= buf(t-1),
      // whose reads were register-consumed by every wave before it got here)
      asm volatile("s_waitcnt vmcnt(0)" ::: "memory");
      __builtin_amdgcn_s_barrier();
      if (t + 1 < 16) stage(buf ^ 1, t + 1);
    } else {
      if (t + 1 < 16) { stage(buf ^ 1, t + 1); __syncthreads(); }
    }
    const char* ab = smem + kh * 16384 + buf * 8192;
    const char* bb = smem + 32768 + kh * 16384 + buf * 8192;
    #pragma unroll
    for (int kk = 0; kk < 2; ++kk) {
      int col = kk * 32 + lg * 8;
      half8 af[2];
      #pragma unroll
      for (int mt = 0; mt < 2; ++mt) {
        int row = mw * 32 + mt * 16 + lr;
        af[mt] = *(const half8*)(ab + ((row * 128 + col * 2) ^ ((row & 7) << 4)));
      }
      __builtin_amdgcn_s_setprio(1);
      #pragma unroll
      for (int nt = 0; nt < 4; ++nt) {
        int row = nt * 16 + lr;
        half8 bfr = *(const half8*)(bb + ((row * 128 + col * 2) ^ ((row & 7) << 4)));
        #pragma unroll
        for (int mt = 0; mt < 2; ++mt)
          acc[mt][nt] = __builtin_amdgcn_mfma_f32_16x16x32_f16(af[mt], bfr, acc[mt][nt], 0, 0, 0);
      }
      __builtin_amdgcn_s_setprio(0);
    }
    if constexpr (!A16) __syncthreads();
  }

  __syncthreads();  // all compute done before smem reuse

  // reduce K-halves: kh=1 publishes (XOR-swizzled vs 128B-stride conflicts)
  if (kh == 1) {
    #pragma unroll
    for (int mt = 0; mt < 2; ++mt)
      #pragma unroll
      for (int nt = 0; nt < 4; ++nt) {
        int idx = mt * 4 + nt;
        *(floatx4*)(smem + mw * 8192 + lane * 128 + ((idx ^ (lane & 7)) * 16)) = acc[mt][nt];
      }
  }
  __syncthreads();
  if (kh == 0) {
    #pragma unroll
    for (int mt = 0; mt < 2; ++mt)
      #pragma unroll
      for (int nt = 0; nt < 4; ++nt) {
        int idx = mt * 4 + nt;
        acc[mt][nt] += *(const floatx4*)(smem + mw * 8192 + lane * 128 + ((idx ^ (lane & 7)) * 16));
        #pragma unroll
        for (int r = 0; r < 4; ++r) {
          int p = p0 + mw * 32 + mt * 16 + lg * 4 + r;
          int d = nt * 16 + lr;
          out[((size_t)(b * NL + p)) * ND + d] = acc[mt][nt][r];
        }
      }
  }
}

extern "C" void kernel_launch(void* const* d_in, const int* in_sizes, int n_in,
                              void* d_out, int out_size, void* d_ws, size_t ws_size,
                              hipStream_t stream) {
  (void)in_sizes; (void)n_in; (void)out_size;
  const float* Q = (const float*)d_in[0];
  const float* K = (const float*)d_in[1];
  const float* V = (const float*)d_in[2];
  const float* M = (const float*)d_in[3];
  float* out = (float*)d_out;

  char* ws = (char*)d_ws;
  _Float16* Vtp  = (_Float16*)ws;                      // 4 MB  [b][d][s] kappa+swz
  _Float16* Vatt = (_Float16*)(ws + (4u << 20));       // 4 MB  [b][d][l] swz
  _Float16* Kh   = (_Float16*)(ws + (8u << 20));       // 4 MB  [b][s][e] swz
  _Float16* Mh   = (_Float16*)(ws + (12u << 20));      // 8 MB  [p][l]    swz
  bool big = ws_size >= (size_t)(20u << 20);

  if (big) {
    prep_k<<<1536, 256, 0, stream>>>(V, K, Vtp, Kh, 1);
    attn_k<true><<<dim3(16, 16), 512, 0, stream>>>(Q, Kh, Vtp, Vatt, M, Mh);
    mix_k<true><<<dim3(32, 16), 256, 0, stream>>>(Mh, Vatt, out);
  } else {
    prep_k<<<512, 256, 0, stream>>>(V, K, Vtp, Kh, 0);
    attn_k<false><<<dim3(16, 16), 512, 0, stream>>>(Q, K, Vtp, Vatt, nullptr, nullptr);
    mix_k<false><<<dim3(32, 16), 256, 0, stream>>>(M, Vatt, out);
  }
}

// Round 26
// 51.428 us; speedup vs baseline: 1.0903x; 1.0057x over previous
//
#include <hip/hip_runtime.h>

#define NB 16
#define NL 2048
#define NS 2048
#define NE 64
#define ND 64

typedef float floatx4 __attribute__((ext_vector_type(4)));
typedef _Float16 half8 __attribute__((ext_vector_type(8)));
typedef __fp16 half2v __attribute__((ext_vector_type(2)));  // cvt_pkrtz's return type

union H8 { half8 v; half2v h2[4]; };

__device__ __forceinline__ half8 cvt8(floatx4 a, floatx4 b) {
  H8 h;
  h.h2[0] = __builtin_amdgcn_cvt_pkrtz(a[0], a[1]);
  h.h2[1] = __builtin_amdgcn_cvt_pkrtz(a[2], a[3]);
  h.h2[2] = __builtin_amdgcn_cvt_pkrtz(b[0], b[1]);
  h.h2[3] = __builtin_amdgcn_cvt_pkrtz(b[2], b[3]);
  return h.v;
}

// async 16B/lane global->LDS. LDS dest is wave-uniform base + lane*16.
__device__ __forceinline__ void async16(void* l, const void* g) {
  __builtin_amdgcn_global_load_lds((__attribute__((address_space(1))) void*)g,
                                   (__attribute__((address_space(3))) void*)l, 16, 0, 0);
}

// kappa: contraction-slot -> key permutation making PV B-frag lane-local
// (closed within each 32-key group). kinv is its inverse.
__device__ __forceinline__ int kinv(int y) {
  return (y & 0x23) | ((y & 8) << 1) | ((y & 4) << 1) | ((y & 16) >> 2);
}

// ---------- prep: blocks [0,512) V-transpose, [512,1536) K-convert ----------
__global__ __launch_bounds__(256) void prep_k(const float* __restrict__ V,
                                              const float* __restrict__ K,
                                              _Float16* __restrict__ Vt,
                                              _Float16* __restrict__ Kh,
                                              int do_k) {
  __shared__ __align__(16) _Float16 Vl[64][72];  // [d][kappa-pos]
  const int bid = blockIdx.x;
  const int t = threadIdx.x;

  if (bid < 512) {  // ---- V -> V^T fp16 [b][d][s], kappa-permuted + swizzled
    const int b = bid >> 5;
    const int s0 = (bid & 31) * 64;
    {
      int sl = t & 63;
      int dg = t >> 6;
      const float* src = V + ((size_t)(b * NS + s0 + sl)) * ND + dg * 16;
      int x = kinv(sl);
      #pragma unroll
      for (int c = 0; c < 4; ++c) {
        floatx4 v = *(const floatx4*)(src + c * 4);
        #pragma unroll
        for (int e = 0; e < 4; ++e) Vl[dg * 16 + c * 4 + e][x] = (_Float16)v[e];
      }
    }
    __syncthreads();
    {
      int d = t & 63;
      int xg = t >> 6;
      int dk = (d & 7) << 3;
      #pragma unroll
      for (int h = 0; h < 2; ++h) {
        int x = xg * 16 + h * 8;
        half8 v = *(const half8*)&Vl[d][x];
        *(half8*)(Vt + ((size_t)(b * ND + d)) * NS + s0 + (x ^ dk)) = v;
      }
    }
  } else {  // ---- K fp32 -> fp16, swizzled columns
    if (!do_k) return;
    int c = (bid - 512) * 256 + t;
    int j = c & 7;
    int s = (c >> 3) & (NS - 1);
    int b = c >> 14;
    const float* src = K + ((size_t)(b * NS + s)) * NE + j * 8;
    half8 h = cvt8(*(const floatx4*)src, *(const floatx4*)(src + 4));
    *(half8*)(Kh + ((size_t)(b * NS + s)) * NE + (j ^ (s & 7)) * 8) = h;
  }
}

// ---------- flash attention: 128-q blocks, 128-key tiles, 8 waves -----------
// triple-buffered LDS, ONE barrier/tile; row-sum via MFMA(ones)
// XCD-aware remap: each XCD owns 2 batches -> K/V L2-resident
template<bool KH16>
__global__ __launch_bounds__(512) void attn_k(const float* __restrict__ Q,
                                              const void* __restrict__ Ksrc,
                                              const _Float16* __restrict__ Vtp,
                                              _Float16* __restrict__ Vatt,
                                              const float* __restrict__ Mf,
                                              _Float16* __restrict__ Mh) {
  __shared__ __align__(16) char smem[98304];  // K 3x16K @0, V 3x16K @49152
  const int tid = threadIdx.x;
  const int wid = tid >> 6, lane = tid & 63;
  const int lr = lane & 15, lg = lane >> 4;
  const int g = wid & 1;        // key-half of the 128-key tile (64 keys)
  const int qh = wid >> 1;      // q-quarter (32 q each, 0..3)
  // XCD-aware bijective remap: XCD L%8 hosts batches {2*xcd, 2*xcd+1}
  const int L = blockIdx.y * 16 + blockIdx.x;   // 0..255
  const int b = (L & 7) * 2 + ((L >> 3) & 1);
  const int qx = L >> 4;                        // 0..15
  const int qbase = qx * 128 + qh * 32;
  const _Float16* Kh = (const _Float16*)Ksrc;
  const float* Kf = (const float*)Ksrc;

  // Q B-frags with scale*log2(e) pre-folded. [col=q=lr][k = kk*32+lg*8+j]
  constexpr float SC = 0.18033688f;  // (1/8) * log2(e)
  half8 qf[2][2];
  #pragma unroll
  for (int sub = 0; sub < 2; ++sub)
    #pragma unroll
    for (int kk = 0; kk < 2; ++kk) {
      const float* qp = Q + ((size_t)(b * NL + qbase + sub * 16 + lr)) * NE + kk * 32 + lg * 8;
      floatx4 a = *(const floatx4*)qp, c = *(const floatx4*)(qp + 4);
      qf[sub][kk] = cvt8(a * SC, c * SC);
    }

  half8 ones;
  #pragma unroll
  for (int i = 0; i < 8; ++i) ones[i] = (_Float16)1.0f;

  floatx4 oacc[2][4], lacc[2];
  #pragma unroll
  for (int s = 0; s < 2; ++s) {
    lacc[s] = (floatx4){0.f, 0.f, 0.f, 0.f};
    #pragma unroll
    for (int m = 0; m < 4; ++m) oacc[s][m] = (floatx4){0.f, 0.f, 0.f, 0.f};
  }

  // hoisted swizzled LDS read offsets (invariant across tiles)
  int kOff[4][2], vOff[2][4];
  #pragma unroll
  for (int mt = 0; mt < 4; ++mt)
    #pragma unroll
    for (int kk = 0; kk < 2; ++kk) {
      int row = g * 64 + mt * 16 + lr, col = kk * 32 + lg * 8;
      kOff[mt][kk] = (row * 128 + col * 2) ^ ((row & 7) << 4);
    }
  #pragma unroll
  for (int kk = 0; kk < 2; ++kk)
    #pragma unroll
    for (int mt = 0; mt < 4; ++mt) {
      int row = mt * 16 + lr;
      vOff[kk][mt] = row * 256 + g * 128 + (((kk * 32 + lg * 8) * 2) ^ ((row & 7) << 4));
    }

  // 8 waves stage 32KB per 128-key tile: 2 async16 per wave K, 2 V
  auto stageV = [&](int buf, int s0) {
    #pragma unroll
    for (int i = 0; i < 2; ++i) {
      int co = (wid * 2 + i) * 1024;
      int o = co + lane * 16;
      int row = o >> 8, c16 = (o >> 4) & 15;
      async16(smem + 49152 + buf * 16384 + co,
              Vtp + ((size_t)(b * ND + row)) * NS + s0 + c16 * 8);
    }
  };
  auto stageK = [&](int buf, int s0) {
    if constexpr (KH16) {
      #pragma unroll
      for (int i = 0; i < 2; ++i) {
        int co = (wid * 2 + i) * 1024;
        int o = co + lane * 16;
        int row = o >> 7, c8 = (o >> 4) & 7;
        async16(smem + buf * 16384 + co,
                Kh + ((size_t)(b * NS + s0 + row)) * NE + c8 * 8);
      }
    } else {
      int row = tid >> 2, cg = (tid & 3) * 16;
      const float* kp = Kf + ((size_t)(b * NS + s0 + row)) * NE + cg;
      #pragma unroll
      for (int c = 0; c < 2; ++c) {
        half8 h = cvt8(*(const floatx4*)(kp + c * 8), *(const floatx4*)(kp + c * 8 + 4));
        int col = cg + c * 8;
        *(half8*)(smem + buf * 16384 + ((row * 128 + col * 2) ^ ((row & 7) << 4))) = h;
      }
    }
  };

  stageK(0, 0); stageV(0, 0);

  int br = 0;
  for (int t = 0; t < NS / 128; ++t) {
    int bn = (br == 2) ? 0 : br + 1;
    if (t + 1 < NS / 128) {
      stageK(bn, (t + 1) * 128); stageV(bn, (t + 1) * 128);
      if constexpr (KH16) {
        asm volatile("s_waitcnt vmcnt(4)" ::: "memory");
        __builtin_amdgcn_s_barrier();
      } else __syncthreads();
    } else {
      if constexpr (KH16) {
        asm volatile("s_waitcnt vmcnt(0)" ::: "memory");
        __builtin_amdgcn_s_barrier();
      } else __syncthreads();
    }

    const char* kb = smem + br * 16384;
    const char* vb = smem + 49152 + br * 16384;

    // K A-frags: this wave's 64 keys
    half8 kf[4][2];
    #pragma unroll
    for (int mt = 0; mt < 4; ++mt)
      #pragma unroll
      for (int kk = 0; kk < 2; ++kk)
        kf[mt][kk] = *(const half8*)(kb + kOff[mt][kk]);

    H8 bf[2][2];
    #pragma unroll
    for (int sub = 0; sub < 2; ++sub) {
      floatx4 sacc[4];
      #pragma unroll
      for (int mt = 0; mt < 4; ++mt) sacc[mt] = (floatx4){0.f, 0.f, 0.f, 0.f};
      __builtin_amdgcn_s_setprio(1);
      #pragma unroll
      for (int kk = 0; kk < 2; ++kk)
        #pragma unroll
        for (int mt = 0; mt < 4; ++mt)
          sacc[mt] = __builtin_amdgcn_mfma_f32_16x16x32_f16(kf[mt][kk], qf[sub][kk], sacc[mt], 0, 0, 0);
      __builtin_amdgcn_s_setprio(0);

      // p = exp2(s); pack straight into kappa-local B-frags
      #pragma unroll
      for (int mt = 0; mt < 4; ++mt) {
        float p0 = __builtin_amdgcn_exp2f(sacc[mt][0]);
        float p1 = __builtin_amdgcn_exp2f(sacc[mt][1]);
        float p2 = __builtin_amdgcn_exp2f(sacc[mt][2]);
        float p3 = __builtin_amdgcn_exp2f(sacc[mt][3]);
        bf[sub][mt >> 1].h2[(mt & 1) * 2]     = __builtin_amdgcn_cvt_pkrtz(p0, p1);
        bf[sub][mt >> 1].h2[(mt & 1) * 2 + 1] = __builtin_amdgcn_cvt_pkrtz(p2, p3);
      }
    }

    // PV^T + row-sum via MFMA(ones): lacc[sub] accumulates sum_k P[q,k]
    __builtin_amdgcn_s_setprio(1);
    #pragma unroll
    for (int kk = 0; kk < 2; ++kk) {
      #pragma unroll
      for (int mt = 0; mt < 4; ++mt) {
        half8 vt = *(const half8*)(vb + vOff[kk][mt]);
        oacc[0][mt] = __builtin_amdgcn_mfma_f32_16x16x32_f16(vt, bf[0][kk].v, oacc[0][mt], 0, 0, 0);
        oacc[1][mt] = __builtin_amdgcn_mfma_f32_16x16x32_f16(vt, bf[1][kk].v, oacc[1][mt], 0, 0, 0);
      }
      lacc[0] = __builtin_amdgcn_mfma_f32_16x16x32_f16(ones, bf[0][kk].v, lacc[0], 0, 0, 0);
      lacc[1] = __builtin_amdgcn_mfma_f32_16x16x32_f16(ones, bf[1][kk].v, lacc[1], 0, 0, 0);
    }
    __builtin_amdgcn_s_setprio(0);
    br = bn;
  }

  __syncthreads();  // last tile's reads complete everywhere before smem reuse

  // combine key-halves per q-quarter: g=1 publishes partials; g=0 reduce+store
  {
    char* red = smem + qh * 12288;
    if (g == 1) {
      #pragma unroll
      for (int sub = 0; sub < 2; ++sub)
        #pragma unroll
        for (int mt = 0; mt < 4; ++mt)
          *(floatx4*)(red + lane * 144 + (sub * 4 + mt) * 16) = oacc[sub][mt];
      if (lg == 0) {
        *(float*)(red + 9216 + lr * 8) = lacc[0][0];
        *(float*)(red + 9216 + lr * 8 + 4) = lacc[1][0];
      }
    }
    __syncthreads();
    if (g == 0) {
      #pragma unroll
      for (int sub = 0; sub < 2; ++sub) {
        float lt = lacc[sub][0] + *(const float*)(red + 9216 + lr * 8 + sub * 4);
        float inv = __builtin_amdgcn_rcpf(lt);
        int l = qbase + sub * 16 + lr;
        #pragma unroll
        for (int mt = 0; mt < 4; ++mt) {
          floatx4 o = oacc[sub][mt] + *(const floatx4*)(red + lane * 144 + (sub * 4 + mt) * 16);
          #pragma unroll
          for (int r = 0; r < 4; ++r) {
            int d = mt * 16 + lg * 4 + r;
            int lsw = (l & ~63) | ((l & 63) ^ ((d & 7) << 3));
            Vatt[((size_t)(b * ND + d)) * NL + lsw] = (_Float16)(o[r] * inv);
          }
        }
      }
    }
  }

  // ---- tail: this block converts 1/256 of mlp fp32 -> fp16 (swizzled) ----
  if constexpr (KH16) {
    int mb = blockIdx.y * 16 + blockIdx.x;  // 0..255
    #pragma unroll
    for (int q = 0; q < 4; ++q) {
      int c = mb * 2048 + q * 512 + tid;
      int j = c & 255, p = c >> 8;
      const float* src = Mf + (size_t)p * NL + j * 8;
      half8 h = cvt8(*(const floatx4*)src, *(const floatx4*)(src + 4));
      int jo = (j & ~7) | ((j & 7) ^ (p & 7));
      *(half8*)(Mh + (size_t)p * NL + jo * 8) = h;
    }
  }
}

// ---------- mix: out[b,p,d] = sum_l mlp[p,l] * Vatt^T[(b,d)][l] -------------
// 4 waves (mw M-half, kh K-half); double-buffered 64KB -> 2 blocks/CU;
// single barrier/tile (stage AFTER barrier; reads register-consumed pre-barrier)
// XCD-aware remap: each XCD owns 4 p-tiles -> A-panel L2-resident
template<bool A16>
__global__ __launch_bounds__(256) void mix_k(const void* __restrict__ Asrc,
                                             const _Float16* __restrict__ Bsrc,
                                             float* __restrict__ out) {
  // A0 @0, A1 @16384, B0 @32768, B1 @49152 (each: dbuf 2 x 8KB)
  __shared__ __align__(16) char smem[65536];
  const int tid = threadIdx.x;
  const int wid = tid >> 6, lane = tid & 63;
  const int lr = lane & 15, lg = lane >> 4;
  const int kh = wid & 1;       // K-half
  const int mw = wid >> 1;      // M-half (32 rows)
  // XCD-aware bijective remap of (p-tile, batch): XCD L%8 owns p-tiles {4x..4x+3}
  const int L = blockIdx.y * 32 + blockIdx.x;   // 0..511
  const int i = L >> 3;                          // 0..63
  const int p0 = ((L & 7) * 4 + (i & 3)) * 64;
  const int b = i >> 2;
  const _Float16* Ah = (const _Float16*)Asrc;
  const float* Af = (const float*)Asrc;

  floatx4 acc[2][4];
  #pragma unroll
  for (int mt = 0; mt < 2; ++mt)
    #pragma unroll
    for (int nt = 0; nt < 4; ++nt) acc[mt][nt] = (floatx4){0.f, 0.f, 0.f, 0.f};

  // per tile: wave (kh,mw) stages quarter of A[kh] and B[kh] (8 async16)
  auto stage = [&](int buf, int t) {
    int k0 = kh * (NL / 2) + t * 64;
    if constexpr (A16) {
      #pragma unroll
      for (int i2 = 0; i2 < 4; ++i2) {
        int co = (mw * 4 + i2) * 1024;
        int o = co + lane * 16;
        int row = o >> 7, c8 = (o >> 4) & 7;
        async16(smem + kh * 16384 + buf * 8192 + co,
                Ah + ((size_t)(p0 + row)) * NL + k0 + c8 * 8);
      }
    } else {
      int row = (lane & 31) + mw * 32, cg = (lane >> 5) * 32;
      const float* ap = Af + ((size_t)(p0 + row)) * NL + k0 + cg;
      #pragma unroll
      for (int c = 0; c < 4; ++c) {
        half8 h = cvt8(*(const floatx4*)(ap + c * 8), *(const floatx4*)(ap + c * 8 + 4));
        int col = cg + c * 8;
        *(half8*)(smem + kh * 16384 + buf * 8192 +
                  ((row * 128 + col * 2) ^ ((row & 7) << 4))) = h;
      }
    }
    #pragma unroll
    for (int i2 = 0; i2 < 4; ++i2) {
      int co = (mw * 4 + i2) * 1024;
      int o = co + lane * 16;
      int row = o >> 7, c8 = (o >> 4) & 7;
      async16(smem + 32768 + kh * 16384 + buf * 8192 + co,
              Bsrc + ((size_t)(b * ND + row)) * NL + k0 + c8 * 8);
    }
  };

  stage(0, 0);
  if constexpr (!A16) __syncthreads();

  for (int t = 0; t < 16; ++t) {
    int buf = t & 1;
    if constexpr (A16) {
      // single barrier: drain stage(t), then prefetch t+1 into buf^1 (= buf(t-1),
      // whose reads were register-consumed by every wave before it got here)
      asm volatile("s_waitcnt vmcnt(0)" ::: "memory");
      __builtin_amdgcn_s_barrier();
      if (t + 1 < 16) stage(buf ^ 1, t + 1);
    } else {
      if (t + 1 < 16) { stage(buf ^ 1, t + 1); __syncthreads(); }
    }
    const char* ab = smem + kh * 16384 + buf * 8192;
    const char* bb = smem + 32768 + kh * 16384 + buf * 8192;
    #pragma unroll
    for (int kk = 0; kk < 2; ++kk) {
      int col = kk * 32 + lg * 8;
      half8 af[2];
      #pragma unroll
      for (int mt = 0; mt < 2; ++mt) {
        int row = mw * 32 + mt * 16 + lr;
        af[mt] = *(const half8*)(ab + ((row * 128 + col * 2) ^ ((row & 7) << 4)));
      }
      __builtin_amdgcn_s_setprio(1);
      #pragma unroll
      for (int nt = 0; nt < 4; ++nt) {
        int row = nt * 16 + lr;
        half8 bfr = *(const half8*)(bb + ((row * 128 + col * 2) ^ ((row & 7) << 4)));
        #pragma unroll
        for (int mt = 0; mt < 2; ++mt)
          acc[mt][nt] = __builtin_amdgcn_mfma_f32_16x16x32_f16(af[mt], bfr, acc[mt][nt], 0, 0, 0);
      }
      __builtin_amdgcn_s_setprio(0);
    }
    if constexpr (!A16) __syncthreads();
  }

  __syncthreads();  // all compute done before smem reuse

  // reduce K-halves: kh=1 publishes (XOR-swizzled vs 128B-stride conflicts)
  if (kh == 1) {
    #pragma unroll
    for (int mt = 0; mt < 2; ++mt)
      #pragma unroll
      for (int nt = 0; nt < 4; ++nt) {
        int idx = mt * 4 + nt;
        *(floatx4*)(smem + mw * 8192 + lane * 128 + ((idx ^ (lane & 7)) * 16)) = acc[mt][nt];
      }
  }
  __syncthreads();
  if (kh == 0) {
    #pragma unroll
    for (int mt = 0; mt < 2; ++mt)
      #pragma unroll
      for (int nt = 0; nt < 4; ++nt) {
        int idx = mt * 4 + nt;
        acc[mt][nt] += *(const floatx4*)(smem + mw * 8192 + lane * 128 + ((idx ^ (lane & 7)) * 16));
        #pragma unroll
        for (int r = 0; r < 4; ++r) {
          int p = p0 + mw * 32 + mt * 16 + lg * 4 + r;
          int d = nt * 16 + lr;
          out[((size_t)(b * NL + p)) * ND + d] = acc[mt][nt][r];
        }
      }
  }
}

extern "C" void kernel_launch(void* const* d_in, const int* in_sizes, int n_in,
                              void* d_out, int out_size, void* d_ws, size_t ws_size,
                              hipStream_t stream) {
  (void)in_sizes; (void)n_in; (void)out_size;
  const float* Q = (const float*)d_in[0];
  const float* K = (const float*)d_in[1];
  const float* V = (const float*)d_in[2];
  const float* M = (const float*)d_in[3];
  float* out = (float*)d_out;

  char* ws = (char*)d_ws;
  _Float16* Vtp  = (_Float16*)ws;                      // 4 MB  [b][d][s] kappa+swz
  _Float16* Vatt = (_Float16*)(ws + (4u << 20));       // 4 MB  [b][d][l] swz
  _Float16* Kh   = (_Float16*)(ws + (8u << 20));       // 4 MB  [b][s][e] swz
  _Float16* Mh   = (_Float16*)(ws + (12u << 20));      // 8 MB  [p][l]    swz
  bool big = ws_size >= (size_t)(20u << 20);

  if (big) {
    prep_k<<<1536, 256, 0, stream>>>(V, K, Vtp, Kh, 1);
    attn_k<true><<<dim3(16, 16), 512, 0, stream>>>(Q, Kh, Vtp, Vatt, M, Mh);
    mix_k<true><<<dim3(32, 16), 256, 0, stream>>>(Mh, Vatt, out);
  } else {
    prep_k<<<512, 256, 0, stream>>>(V, K, Vtp, Kh, 0);
    attn_k<false><<<dim3(16, 16), 512, 0, stream>>>(Q, K, Vtp, Vatt, nullptr, nullptr);
    mix_k<false><<<dim3(32, 16), 256, 0, stream>>>(M, Vatt, out);
  }
}